// Round 11
// baseline (1011.135 us; speedup 1.0000x reference)
//
#include <hip/hip_runtime.h>
#include <hip/hip_bf16.h>

typedef unsigned short u16;
typedef __attribute__((ext_vector_type(8))) short bf16x8;
typedef __attribute__((ext_vector_type(4))) float f32x4;
typedef __attribute__((ext_vector_type(4))) int i32x4;
typedef __attribute__((ext_vector_type(2))) int i32x2;

#define NPROD 50001
#define SEQ 100
#define BATCH 256
#define HID 256

// Bbuf chunks: layer0 16n*4g*13ks*64ln = 53248, layer1 16*4*16*64 = 65536
#define L0_CHUNKS 53248
#define L1_CHUNKS 65536
#define L1_BASE_U16 (L0_CHUNKS * 8)

// bf16 NaN sentinel: impossible as h output (|h| < 1 strictly)
#define SENT16 0x7FC0u

__device__ inline float bf2f(u16 u) {
    union { unsigned u; float f; } v; v.u = ((unsigned)u) << 16; return v.f;
}
__device__ inline u16 f2bf(float x) {
    unsigned u = __float_as_uint(x);
    unsigned r = (u + 0x7FFFu + ((u >> 16) & 1u)) >> 16;
    return (u16)r;
}
__device__ inline float sigm(float x) { return 1.f / (1.f + __expf(-x)); }
__device__ inline float tanh_(float x) { return 1.f - 2.f / (1.f + __expf(2.f * x)); }

// MALL-coherent (bypass L1+L2): sc0 sc1. Batched: many in flight, one s_waitcnt.
__device__ inline i32x4 ld16_nc(const void* p) {
    i32x4 r;
    asm volatile("global_load_dwordx4 %0, %1, off sc0 sc1" : "=&v"(r) : "v"(p) : "memory");
    return r;
}
__device__ inline void st8_nc(void* p, i32x2 v) {
    asm volatile("global_store_dwordx2 %0, %1, off sc0 sc1" :: "v"(p), "v"(v) : "memory");
}
__device__ inline void st4_nc(void* p, int v) {
    asm volatile("global_store_dword %0, %1, off sc0 sc1" :: "v"(p), "v"(v) : "memory");
}
__device__ inline void vmcnt0() {
    asm volatile("s_waitcnt vmcnt(0)" ::: "memory");
    __builtin_amdgcn_sched_barrier(0);
}
__device__ inline bool clean16(i32x4 v) {
    bool ok = true;
#pragma unroll
    for (int k = 0; k < 4; ++k) {
        unsigned u = (unsigned)v[k];
        ok = ok && ((u & 0xFFFFu) != SENT16) && ((u >> 16) != SENT16);
    }
    return ok;
}
// flag spin: 4 slots per lane, pass when all >= tgt
__device__ inline void spin4(const int* p, int tgt) {
    for (;;) {
        i32x4 v = ld16_nc(p);
        vmcnt0();
        if (v[0] >= tgt && v[1] >= tgt && v[2] >= tgt && v[3] >= tgt) return;
        __builtin_amdgcn_s_sleep(1);
    }
}

// ---------------- weight prep: f32 -> bf16 MFMA B-fragments + bias sums ----------------
__global__ __launch_bounds__(256) void prep_kernel(
    const float* __restrict__ Wih0, const float* __restrict__ Whh0,
    const float* __restrict__ Wih1, const float* __restrict__ Whh1,
    const float* __restrict__ bih0, const float* __restrict__ bhh0,
    const float* __restrict__ bih1, const float* __restrict__ bhh1,
    u16* __restrict__ Bbuf, float* __restrict__ bsum)
{
    int idx = blockIdx.x * 256 + threadIdx.x;
    if (idx < L0_CHUNKS + L1_CHUNKS) {
        int L, KS, i;
        if (idx < L0_CHUNKS) { L = 0; KS = 13; i = idx; }
        else { L = 1; KS = 16; i = idx - L0_CHUNKS; }
        int ln = i & 63; int q = i >> 6;
        int ks = q % KS; int q2 = q / KS;
        int g = q2 & 3; int n = q2 >> 2;
        int grow = g * 256 + n * 16 + (ln & 15);
        int k0 = ks * 32 + (ln >> 4) * 8;
        bf16x8 v;
#pragma unroll
        for (int e = 0; e < 8; ++e) {
            int k = k0 + e;
            float f;
            if (L == 0) f = (k < 160) ? Wih0[(size_t)grow * 160 + k] : Whh0[(size_t)grow * 256 + (k - 160)];
            else        f = (k < 256) ? Wih1[(size_t)grow * 256 + k] : Whh1[(size_t)grow * 256 + (k - 256)];
            v[e] = (short)f2bf(f);
        }
        size_t off = (size_t)(L ? L1_BASE_U16 : 0) + ((size_t)i) * 8;
        *(bf16x8*)(Bbuf + off) = v;
    } else if (idx < L0_CHUNKS + L1_CHUNKS + 2048) {
        int j = idx - (L0_CHUNKS + L1_CHUNKS);
        int L = j >> 10, r = j & 1023;
        bsum[j] = L ? (bih1[r] + bhh1[r]) : (bih0[r] + bhh0[r]);
    }
}

// ---------------- poison: fill h0s slots 1..15 + h1s slots 1..100 with sentinel ----------------
__global__ __launch_bounds__(256) void poison_kernel(char* h0s, char* h1s)
{
    size_t i = (size_t)blockIdx.x * 256 + threadIdx.x;
    const int S = (int)0x7FC07FC0u;
    i32x4 v = { S, S, S, S };
    const size_t h0c = (size_t)15 * 131072 / 16;    // 122880 chunks
    const size_t h1c = (size_t)100 * 131072 / 16;   // 819200 chunks
    if (i < h0c) *(i32x4*)(h0s + 131072 + i * 16) = v;
    else if (i < h0c + h1c) *(i32x4*)(h1s + 131072 + (i - h0c) * 16) = v;
}

// ---------------- embedding + mean-pool + category ----------------
__global__ __launch_bounds__(256) void embed_kernel(
    const int* __restrict__ seqs, const int* __restrict__ p2c,
    const float* __restrict__ ptab, const float* __restrict__ ctab,
    u16* __restrict__ combined)
{
    int gw = (blockIdx.x * 256 + threadIdx.x) >> 6;
    int ln = threadIdx.x & 63;
    const int* basket = seqs + (size_t)gw * 20;
    int idx = (ln < 20) ? basket[ln] : 0;
    unsigned long long nz = __ballot(idx != 0);
    int fp = 0;
    if (nz != 0ull) {
        int fl = __ffsll(nz) - 1;
        fp = __shfl(idx, fl);
    }
    float a0 = 0.f, a1 = 0.f;
#pragma unroll
    for (int k = 0; k < 20; ++k) {
        int pk = __shfl(idx, k);
        float2 v = *(const float2*)(ptab + (size_t)pk * 128 + 2 * ln);
        a0 += v.x; a1 += v.y;
    }
    const float inv = 1.0f / 20.0f;
    u16* crow = combined + (size_t)gw * 160;
    ushort2 st; st.x = f2bf(a0 * inv); st.y = f2bf(a1 * inv);
    ((ushort2*)crow)[ln] = st;
    int cat = p2c[fp];
    if (ln < 16) {
        float2 cv = *(const float2*)(ctab + (size_t)cat * 32 + 2 * ln);
        ushort2 s2; s2.x = f2bf(cv.x); s2.y = f2bf(cv.y);
        ((ushort2*)(crow + 128))[ln] = s2;
    }
}

// ---------------- persistent 2-layer LSTM, sentinel-validated exchange ----------------
// 128 WGs = 2 layers x 4 batch-slices(m: 64 rows) x 16 col-slices(n: 16 h-cols).
// h data IS the flag: slots pre-poisoned with bf16 NaN 0x7FC0 (impossible as
// real h since |h|<1); consumers spin-load the data until sentinel-free
// (probe 16B, then full 128B). Producers only ISSUE stores: no store-ack
// wait, no flag, no end-of-step barrier. One surviving flag array: L1's
// ring flags (deferred post), gating L0's h0-slot reuse with 14-step slack;
// L1 re-poisons h0 slot u&15 at its step u (both readers provably done).
template <int LAYER>
__device__ void lstm_wg(int m, int n,
    const u16* __restrict__ combined, const u16* __restrict__ Bbuf,
    const float* __restrict__ bsum,
    u16* h0s, u16* h1s, int* flags, unsigned char* smem)
{
    constexpr int KS = (LAYER == 0) ? 13 : 16;
    const int tid = threadIdx.x;
    const int wv = tid >> 6, ln = tid & 63;
    const int c0 = ln & 15, kq = ln >> 4;

    // ---- preload B fragments: wave wv holds gate wv, 16 cols ----
    bf16x8 Bf[KS];
#pragma unroll
    for (int ks = 0; ks < KS; ++ks) {
        size_t off = (size_t)(LAYER ? L1_BASE_U16 : 0) +
                     ((size_t)(((n * 4 + wv) * KS + ks) * 64 + ln)) * 8;
        Bf[ks] = *(const bf16x8*)(Bbuf + off);
    }
    const float bias = bsum[LAYER * 1024 + wv * 256 + n * 16 + c0];

    float cst[4] = {0.f, 0.f, 0.f, 0.f};
    const int srow = tid >> 2, sl4 = tid & 3;     // staging: 4 threads per row
    const int brow_s = m * 64 + srow;
    const char* h0b = (const char*)h0s;
    const char* h1b = (const char*)h1s;
    unsigned char* rowp = smem + srow * 1024;
    const int xv = (srow & 7) << 4;
    // ring flag line (v&31, m): flags + ((v&31)*4 + m)*16, 16 slots (n)

    for (int t = 0; t < SEQ; ++t) {
        // ---- sentinel-validated staging loads ----
        if (LAYER == 0) {
            i32x4 xb[5];
            const i32x4* xs = (const i32x4*)(combined + ((size_t)brow_s * SEQ + t) * 160) + sl4 * 5;
#pragma unroll
            for (int j = 0; j < 5; ++j) xb[j] = xs[j];
            const char* hsrc = h0b + (size_t)(t & 15) * 131072 + (size_t)brow_s * 512 + sl4 * 128;
            i32x4 hb[8];
            for (;;) {                                   // probe 16B
                i32x4 p = ld16_nc(hsrc);
                vmcnt0();
                if (clean16(p)) { hb[0] = p; break; }
                __builtin_amdgcn_s_sleep(2);
            }
            for (;;) {                                   // full 128B
#pragma unroll
                for (int j = 1; j < 8; ++j) hb[j] = ld16_nc(hsrc + j * 16);
                vmcnt0();
                bool ok = true;
#pragma unroll
                for (int j = 1; j < 8; ++j) ok = ok && clean16(hb[j]);
                if (ok) break;
                __builtin_amdgcn_s_sleep(2);
            }
#pragma unroll
            for (int j = 0; j < 5; ++j)
                *(i32x4*)(rowp + ((sl4 * 80 + 16 * j) ^ xv)) = xb[j];
#pragma unroll
            for (int j = 0; j < 8; ++j)
                *(i32x4*)(rowp + ((320 + sl4 * 128 + 16 * j) ^ xv)) = hb[j];
        } else {
            const char* h0src = h0b + (size_t)((t + 1) & 15) * 131072 + (size_t)brow_s * 512 + sl4 * 128;
            const char* h1src = h1b + (size_t)t * 131072 + (size_t)brow_s * 512 + sl4 * 128;
            i32x4 ha[8], hb[8];
            for (;;) {                                   // probe both
                i32x4 pa = ld16_nc(h0src);
                i32x4 pb = ld16_nc(h1src);
                vmcnt0();
                if (clean16(pa) && clean16(pb)) { ha[0] = pa; hb[0] = pb; break; }
                __builtin_amdgcn_s_sleep(2);
            }
            for (;;) {                                   // full both
#pragma unroll
                for (int j = 1; j < 8; ++j) { ha[j] = ld16_nc(h0src + j * 16); hb[j] = ld16_nc(h1src + j * 16); }
                vmcnt0();
                bool ok = true;
#pragma unroll
                for (int j = 1; j < 8; ++j) ok = ok && clean16(ha[j]) && clean16(hb[j]);
                if (ok) break;
                __builtin_amdgcn_s_sleep(2);
            }
#pragma unroll
            for (int j = 0; j < 8; ++j) {
                *(i32x4*)(rowp + ((sl4 * 128 + 16 * j) ^ xv)) = ha[j];
                *(i32x4*)(rowp + ((512 + sl4 * 128 + 16 * j) ^ xv)) = hb[j];
            }
        }
        __syncthreads();    // all spins done (each thread drained own stores via vmcnt0)

        // deferred ring post: "L1 done step t-1 incl. its poisons" (safe: all
        // threads' prior-step stores drained by their spin vmcnt0 + barrier)
        if (LAYER == 1 && t > 0 && tid == 0)
            st4_nc(flags + (((t - 1) & 31) * 4 + m) * 16 + n, t);

        // ---- MFMA: wave wv -> gate wv, 64 rows x 16 cols ----
        f32x4 acc[4];
#pragma unroll
        for (int tm = 0; tm < 4; ++tm) {
            acc[tm] = f32x4{ bias, bias, bias, bias };
            const unsigned char* rp = smem + (tm * 16 + c0) * 1024;
            const int xr = (c0 & 7) << 4;
#pragma unroll
            for (int ks = 0; ks < KS; ++ks) {
                bf16x8 af = *(const bf16x8*)(rp + ((ks * 64 + kq * 16) ^ xr));
                acc[tm] = __builtin_amdgcn_mfma_f32_16x16x32_bf16(af, Bf[ks], acc[tm], 0, 0, 0);
            }
        }
        __syncthreads();   // all A reads done -> overlay gx

        // ---- gate exchange: gx[g][row64][col16], stride 20, col-XOR swizzle ----
        float* gx = (float*)smem;
#pragma unroll
        for (int tm = 0; tm < 4; ++tm) {
            int cs = c0 ^ ((((tm << 1) + (kq >> 1)) & 3) << 2);
#pragma unroll
            for (int r = 0; r < 4; ++r)
                gx[(wv * 64 + tm * 16 + kq * 4 + r) * 20 + cs] = acc[tm][r];
        }
        // L0: ring wait (h0 slot (t+1)&15 reuse) folded into the gx barrier;
        // poisoned at L1 step t-15, released by ring flag value t-14.
        if (LAYER == 0 && t >= 15 && tid < 4)
            spin4(flags + (((t - 15) & 31) * 4 + m) * 16 + tid * 4, t - 14);
        __syncthreads();

        // ---- activations: thread owns (row ln, cols wv*4..+3) ----
        float hv[4];
        {
            int colx = ((ln >> 3) & 3) << 2;
#pragma unroll
            for (int j = 0; j < 4; ++j) {
                int col = (wv * 4 + j) ^ colx;
                float iv = gx[(0 * 64 + ln) * 20 + col];
                float fv = gx[(1 * 64 + ln) * 20 + col];
                float gv = gx[(2 * 64 + ln) * 20 + col];
                float ov = gx[(3 * 64 + ln) * 20 + col];
                float cn = sigm(fv) * cst[j] + sigm(iv) * tanh_(gv);
                cst[j] = cn;
                hv[j] = sigm(ov) * tanh_(cn);
            }
        }
        // ---- store phase: ISSUE only (no ack wait, no flag) ----
        {
            int browo = m * 64 + ln;
            i32x2 u2;
            u2[0] = (int)((unsigned)f2bf(hv[0]) | ((unsigned)f2bf(hv[1]) << 16));
            u2[1] = (int)((unsigned)f2bf(hv[2]) | ((unsigned)f2bf(hv[3]) << 16));
            if (LAYER == 0) {
                unsigned* o = (unsigned*)h0s + (size_t)((t + 1) & 15) * 32768 + (size_t)browo * 128 + n * 8 + wv * 2;
                st8_nc(o, u2);
            } else {
                unsigned* o = (unsigned*)h1s + (size_t)(t + 1) * 32768 + (size_t)browo * 128 + n * 8 + wv * 2;
                st8_nc(o, u2);
                // re-poison h0 slot t&15 (readers L0 step t / L1 step t-1 done)
                i32x2 sv; sv[0] = (int)0x7FC07FC0u; sv[1] = (int)0x7FC07FC0u;
                unsigned* pp = (unsigned*)h0s + (size_t)(t & 15) * 32768 + (size_t)browo * 128 + n * 8 + wv * 2;
                st8_nc(pp, sv);
            }
        }
        __syncthreads();   // gx reads done before next step's stage writes
    }
}

__global__ __launch_bounds__(256, 1) void lstm_kernel(
    const u16* __restrict__ combined, const u16* __restrict__ Bbuf,
    const float* __restrict__ bsum,
    u16* h0s, u16* h1s, int* flags)
{
    __shared__ __align__(16) unsigned char smem[65536];
    int bid = blockIdx.x;
    int L = bid >> 6, r = bid & 63;
    int m = r >> 4, n = r & 15;
    if (L == 0)
        lstm_wg<0>(m, n, combined, Bbuf, bsum, h0s, h1s, flags, smem);
    else
        lstm_wg<1>(m, n, combined, Bbuf, bsum, h0s, h1s, flags, smem);
}

// ---------------- attention pooling + fc1 ----------------
// h1s layout: [t+1][256 rows][256 cols] bf16 (slot stride 65536 u16)
__global__ __launch_bounds__(256) void attn_kernel(
    const u16* __restrict__ h1s, const float* __restrict__ aw, const float* __restrict__ ab,
    const float* __restrict__ fc1w, const float* __restrict__ fc1b,
    float* __restrict__ attw_out, u16* __restrict__ xbf)
{
    int b = blockIdx.x, tid = threadIdx.x, wv = tid >> 6, ln = tid & 63;
    __shared__ float s_aw[256];
    __shared__ float s_sc[104];
    __shared__ float s_red[8];
    __shared__ float s_ctx[256];
    s_aw[tid] = aw[tid];
    __syncthreads();
    for (int t = wv; t < SEQ; t += 4) {
        const u16* hr = h1s + (size_t)(t + 1) * 65536 + (size_t)b * 256;
        ushort4 hv = ((const ushort4*)hr)[ln];
        float pval = bf2f(hv.x) * s_aw[4 * ln] + bf2f(hv.y) * s_aw[4 * ln + 1] +
                     bf2f(hv.z) * s_aw[4 * ln + 2] + bf2f(hv.w) * s_aw[4 * ln + 3];
#pragma unroll
        for (int off = 32; off; off >>= 1) pval += __shfl_xor(pval, off);
        if (ln == 0) s_sc[t] = pval + ab[0];
    }
    __syncthreads();
    float v = (tid < SEQ) ? s_sc[tid] : -1e30f;
    float m = v;
#pragma unroll
    for (int off = 32; off; off >>= 1) m = fmaxf(m, __shfl_xor(m, off));
    if (ln == 0) s_red[wv] = m;
    __syncthreads();
    m = fmaxf(fmaxf(s_red[0], s_red[1]), fmaxf(s_red[2], s_red[3]));
    float e = (tid < SEQ) ? __expf(v - m) : 0.f;
    float ss = e;
#pragma unroll
    for (int off = 32; off; off >>= 1) ss += __shfl_xor(ss, off);
    if (ln == 0) s_red[4 + wv] = ss;
    __syncthreads();
    float denom = s_red[4] + s_red[5] + s_red[6] + s_red[7];
    float awt = e / denom;
    if (tid < SEQ) {
        attw_out[(size_t)b * SEQ + tid] = awt;
        s_sc[tid] = awt;
    }
    __syncthreads();
    float acc = 0.f;
    for (int t = 0; t < SEQ; ++t)
        acc += s_sc[t] * bf2f(h1s[(size_t)(t + 1) * 65536 + (size_t)b * 256 + tid]);
    s_ctx[tid] = acc;
    __syncthreads();
    if (tid < 128) {
        const float* wr = fc1w + tid * 256;
        float d = fc1b[tid];
        for (int k = 0; k < 256; k += 4) {
            float4 w4 = *(const float4*)(wr + k);
            d += w4.x * s_ctx[k] + w4.y * s_ctx[k + 1] + w4.z * s_ctx[k + 2] + w4.w * s_ctx[k + 3];
        }
        float x = fmaxf(d, 0.f);
        xbf[b * 128 + tid] = f2bf(x);
    }
}

// ---------------- fc2: logits = x @ fc2_w^T + b ----------------
__global__ __launch_bounds__(256) void fc2_kernel(
    const u16* __restrict__ xbf, const float* __restrict__ w,
    const float* __restrict__ bias, float* __restrict__ out)
{
    int n0 = blockIdx.x * 16;
    int tid = threadIdx.x, wv = tid >> 6, ln = tid & 63;
    int c0 = ln & 15, kq = ln >> 4;
    int n = n0 + c0;
    int nc = (n > 50000) ? 50000 : n;
    bf16x8 Bf[4];
#pragma unroll
    for (int ks = 0; ks < 4; ++ks) {
        const float* src = w + (size_t)nc * 128 + ks * 32 + kq * 8;
        bf16x8 tb;
#pragma unroll
        for (int i = 0; i < 8; ++i) tb[i] = (short)f2bf(src[i]);
        Bf[ks] = tb;
    }
    float bv = bias[nc];
    int bb = wv * 64;
#pragma unroll
    for (int q = 0; q < 4; ++q) {
        const u16* xr = xbf + (bb + q * 16 + c0) * 128;
        f32x4 acc = { bv, bv, bv, bv };
#pragma unroll
        for (int ks = 0; ks < 4; ++ks) {
            bf16x8 a = *(const bf16x8*)(xr + ks * 32 + kq * 8);
            acc = __builtin_amdgcn_mfma_f32_16x16x32_bf16(a, Bf[ks], acc, 0, 0, 0);
        }
        if (n <= 50000) {
#pragma unroll
            for (int r = 0; r < 4; ++r)
                out[(size_t)(bb + q * 16 + kq * 4 + r) * 50001 + n] = acc[r];
        }
    }
}

extern "C" void kernel_launch(void* const* d_in, const int* in_sizes, int n_in,
                              void* d_out, int out_size, void* d_ws, size_t ws_size,
                              hipStream_t stream) {
    (void)in_sizes; (void)n_in; (void)out_size; (void)ws_size;
    const int*   seqs = (const int*)d_in[0];
    const int*   p2c  = (const int*)d_in[1];
    const float* ptab = (const float*)d_in[2];
    const float* ctab = (const float*)d_in[3];
    const float* Wih0 = (const float*)d_in[4];
    const float* Whh0 = (const float*)d_in[5];
    const float* bih0 = (const float*)d_in[6];
    const float* bhh0 = (const float*)d_in[7];
    const float* Wih1 = (const float*)d_in[8];
    const float* Whh1 = (const float*)d_in[9];
    const float* bih1 = (const float*)d_in[10];
    const float* bhh1 = (const float*)d_in[11];
    const float* aw   = (const float*)d_in[12];
    const float* ab   = (const float*)d_in[13];
    const float* fc1w = (const float*)d_in[14];
    const float* fc1b = (const float*)d_in[15];
    const float* fc2w = (const float*)d_in[16];
    const float* fc2b = (const float*)d_in[17];

    char* wsb = (char*)d_ws;
    int*   flags    = (int*)wsb;                     // 64KB (ring flag lines)
    u16*   h0s      = (u16*)(wsb + 65536);           // 16 slots x 131072 = 2097152
    u16*   h1s      = (u16*)(wsb + 2162688);         // 101 slots x 131072 = 13238272
    u16*   Bbuf     = (u16*)(wsb + 15400960);        // 1900544
    float* bsum     = (float*)(wsb + 17301504);      // 8192
    u16*   combined = (u16*)(wsb + 17309696);        // 8192000
    u16*   xbf      = (u16*)(wsb + 25501696);        // 65536
    float* logits   = (float*)d_out;
    float* attw_out = logits + (size_t)BATCH * NPROD;

    // zero: flags + h0s slot 0 (contiguous); h1s slot 0
    (void)hipMemsetAsync(d_ws, 0, 65536 + 131072, stream);
    (void)hipMemsetAsync(h1s, 0, 131072, stream);
    prep_kernel<<<472, 256, 0, stream>>>(Wih0, Whh0, Wih1, Whh1, bih0, bhh0, bih1, bhh1, Bbuf, bsum);
    poison_kernel<<<3680, 256, 0, stream>>>((char*)h0s, (char*)h1s);
    embed_kernel<<<6400, 256, 0, stream>>>(seqs, p2c, ptab, ctab, combined);
    lstm_kernel<<<128, 256, 0, stream>>>(combined, Bbuf, bsum, h0s, h1s, flags);
    attn_kernel<<<256, 256, 0, stream>>>(h1s, aw, ab, fc1w, fc1b, attw_out, xbf);
    fc2_kernel<<<3126, 256, 0, stream>>>(xbf, fc2w, fc2b, logits);
}

// Round 12
// 662.377 us; speedup vs baseline: 1.5265x; 1.5265x over previous
//
#include <hip/hip_runtime.h>
#include <hip/hip_bf16.h>

typedef unsigned short u16;
typedef __attribute__((ext_vector_type(8))) short bf16x8;
typedef __attribute__((ext_vector_type(4))) float f32x4;
typedef __attribute__((ext_vector_type(4))) int i32x4;
typedef __attribute__((ext_vector_type(2))) int i32x2;

#define NPROD 50001
#define SEQ 100
#define BATCH 256
#define HID 256

// Bbuf chunks: layer0 16n*4g*13ks*64ln = 53248, layer1 16*4*16*64 = 65536
#define L0_CHUNKS 53248
#define L1_CHUNKS 65536
#define L1_BASE_U16 (L0_CHUNKS * 8)

__device__ inline float bf2f(u16 u) {
    union { unsigned u; float f; } v; v.u = ((unsigned)u) << 16; return v.f;
}
__device__ inline u16 f2bf(float x) {
    unsigned u = __float_as_uint(x);
    unsigned r = (u + 0x7FFFu + ((u >> 16) & 1u)) >> 16;
    return (u16)r;
}
__device__ inline float sigm(float x) { return 1.f / (1.f + __expf(-x)); }
__device__ inline float tanh_(float x) { return 1.f - 2.f / (1.f + __expf(2.f * x)); }

// Cross-XCD-coherent (bypass L1+L2): sc0 sc1. Batched: many in flight, one s_waitcnt.
__device__ inline i32x4 ld16_nc(const void* p) {
    i32x4 r;
    asm volatile("global_load_dwordx4 %0, %1, off sc0 sc1" : "=&v"(r) : "v"(p) : "memory");
    return r;
}
__device__ inline void st4_nc(void* p, int v) {
    asm volatile("global_store_dword %0, %1, off sc0 sc1" :: "v"(p), "v"(v) : "memory");
}
__device__ inline void vmcnt0() {
    asm volatile("s_waitcnt vmcnt(0)" ::: "memory");
    __builtin_amdgcn_sched_barrier(0);
}
// parallel flag spin: 4 slots per lane, pass when all >= tgt (signed)
__device__ inline void spin4(const int* p, int tgt) {
    for (;;) {
        i32x4 v = ld16_nc(p);
        if (v[0] >= tgt && v[1] >= tgt && v[2] >= tgt && v[3] >= tgt) return;
        __builtin_amdgcn_s_sleep(1);
    }
}

// ---------------- weight prep: f32 -> bf16 MFMA B-fragments + bias sums ----------------
// Bbuf (per layer): i = ((n*4 + g)*KS + ks)*64 + ln, 8 u16 each.
// grow = g*256 + n*16 + (ln&15); k = ks*32 + (ln>>4)*8 + e; k-concat [x | h].
__global__ __launch_bounds__(256) void prep_kernel(
    const float* __restrict__ Wih0, const float* __restrict__ Whh0,
    const float* __restrict__ Wih1, const float* __restrict__ Whh1,
    const float* __restrict__ bih0, const float* __restrict__ bhh0,
    const float* __restrict__ bih1, const float* __restrict__ bhh1,
    u16* __restrict__ Bbuf, float* __restrict__ bsum)
{
    int idx = blockIdx.x * 256 + threadIdx.x;
    if (idx < L0_CHUNKS + L1_CHUNKS) {
        int L, KS, i;
        if (idx < L0_CHUNKS) { L = 0; KS = 13; i = idx; }
        else { L = 1; KS = 16; i = idx - L0_CHUNKS; }
        int ln = i & 63; int q = i >> 6;
        int ks = q % KS; int q2 = q / KS;
        int g = q2 & 3; int n = q2 >> 2;
        int grow = g * 256 + n * 16 + (ln & 15);
        int k0 = ks * 32 + (ln >> 4) * 8;
        bf16x8 v;
#pragma unroll
        for (int e = 0; e < 8; ++e) {
            int k = k0 + e;
            float f;
            if (L == 0) f = (k < 160) ? Wih0[(size_t)grow * 160 + k] : Whh0[(size_t)grow * 256 + (k - 160)];
            else        f = (k < 256) ? Wih1[(size_t)grow * 256 + k] : Whh1[(size_t)grow * 256 + (k - 256)];
            v[e] = (short)f2bf(f);
        }
        size_t off = (size_t)(L ? L1_BASE_U16 : 0) + ((size_t)i) * 8;
        *(bf16x8*)(Bbuf + off) = v;
    } else if (idx < L0_CHUNKS + L1_CHUNKS + 2048) {
        int j = idx - (L0_CHUNKS + L1_CHUNKS);
        int L = j >> 10, r = j & 1023;
        bsum[j] = L ? (bih1[r] + bhh1[r]) : (bih0[r] + bhh0[r]);
    }
}

// ---------------- embedding + mean-pool + category ----------------
__global__ __launch_bounds__(256) void embed_kernel(
    const int* __restrict__ seqs, const int* __restrict__ p2c,
    const float* __restrict__ ptab, const float* __restrict__ ctab,
    u16* __restrict__ combined)
{
    int gw = (blockIdx.x * 256 + threadIdx.x) >> 6;
    int ln = threadIdx.x & 63;
    const int* basket = seqs + (size_t)gw * 20;
    int idx = (ln < 20) ? basket[ln] : 0;
    unsigned long long nz = __ballot(idx != 0);
    int fp = 0;
    if (nz != 0ull) {
        int fl = __ffsll(nz) - 1;
        fp = __shfl(idx, fl);
    }
    float a0 = 0.f, a1 = 0.f;
#pragma unroll
    for (int k = 0; k < 20; ++k) {
        int pk = __shfl(idx, k);
        float2 v = *(const float2*)(ptab + (size_t)pk * 128 + 2 * ln);
        a0 += v.x; a1 += v.y;
    }
    const float inv = 1.0f / 20.0f;
    u16* crow = combined + (size_t)gw * 160;
    ushort2 st; st.x = f2bf(a0 * inv); st.y = f2bf(a1 * inv);
    ((ushort2*)crow)[ln] = st;
    int cat = p2c[fp];
    if (ln < 16) {
        float2 cv = *(const float2*)(ctab + (size_t)cat * 32 + 2 * ln);
        ushort2 s2; s2.x = f2bf(cv.x); s2.y = f2bf(cv.y);
        ((ushort2*)(crow + 128))[ln] = s2;
    }
}

// ---------------- persistent 2-layer LSTM, K-split 8-wave WGs ----------------
// 128 WGs x 512 thr = 2 layers x 4 batch-slices(m: 64 rows) x 16 col-slices(n).
// Wave w = (gate g=w&3, K-half kh=w>>2): holds Bf[6..8] (24-32 VGPR) -> fully
// register-resident, no remat/spill (round-10 lesson: Bf+staging didn't fit).
// Partial gate sums exchanged via two LDS gx regions, summed in activation.
// Sync protocol byte-identical to round 10 (per-step flag lines, spin4).
template <int LAYER>
__device__ void lstm_wg(int m, int n,
    const u16* __restrict__ combined, const u16* __restrict__ Bbuf,
    const float* __restrict__ bsum,
    u16* h0s, u16* h1s, int* flags, unsigned char* smem)
{
    constexpr int KS = (LAYER == 0) ? 13 : 16;
    constexpr int H0 = (LAYER == 0) ? 7 : 8;    // kh=0 ks-count
    const int tid = threadIdx.x;
    const int wv = tid >> 6, ln = tid & 63;
    const int c0 = ln & 15, kq = ln >> 4;
    const int g = wv & 3, kh = wv >> 2;
    const int ksbase = kh ? H0 : 0;
    const int kscnt  = kh ? (KS - H0) : H0;

    // ---- preload B fragments: wave (g,kh) holds its K-half of gate g ----
    bf16x8 Bf[8];
#pragma unroll
    for (int ksl = 0; ksl < 8; ++ksl) {
        if (ksl < kscnt) {
            size_t off = (size_t)(LAYER ? L1_BASE_U16 : 0) +
                         ((size_t)(((n * 4 + g) * KS + ksbase + ksl) * 64 + ln)) * 8;
            Bf[ksl] = *(const bf16x8*)(Bbuf + off);
        }
    }
    const float binit = kh ? 0.f : bsum[LAYER * 1024 + g * 256 + n * 16 + c0];

    float cst[2] = {0.f, 0.f};
    const int srow = tid >> 3, sl8 = tid & 7;     // staging: 8 threads per row
    const int brow_s = m * 64 + srow;
    const char* h0b = (const char*)h0s;
    const char* h1b = (const char*)h1s;
    unsigned char* rowp = smem + srow * 1024;
    const int xv = (srow & 7) << 4;
    float* gx = (float*)smem;                      // overlay: gx[2][4][64][20]

    for (int t = 0; t < SEQ; ++t) {
        // ---- lane-parallel polls on per-step 64B lines (identical to r10) ----
        if (LAYER == 0) {
            if (t > 0 && tid < 4)
                spin4(flags + (((t - 1) & 31) * 4 + m) * 16 + tid * 4, t);
            if (t >= 16 && tid >= 4 && tid < 8)   // ring: L1 done step t-16
                spin4(flags + 2048 + (((t - 16) & 31) * 4 + m) * 16 + (tid - 4) * 4, t - 15);
        } else {
            if (tid < 4)                           // L0 done step t
                spin4(flags + ((t & 31) * 4 + m) * 16 + tid * 4, t + 1);
            if (t > 0 && tid >= 4 && tid < 8)      // own group done step t-1
                spin4(flags + 2048 + (((t - 1) & 31) * 4 + m) * 16 + (tid - 4) * 4, t);
        }
        __syncthreads();

        // ---- stage A (64 rows x K bf16) into LDS; 8 threads per row ----
        if (LAYER == 0) {
            // 52 chunks/row: 20 x (combined, plain) + 32 h (h0, nc)
            const char* xrow = (const char*)(combined + ((size_t)brow_s * SEQ + t) * 160);
            const char* hrow = h0b + (size_t)(t & 15) * 131072 + (size_t)brow_s * 512;
            i32x4 vb[7];
#pragma unroll
            for (int i = 0; i < 7; ++i) {
                int c = sl8 + 8 * i;
                if (c < 52) vb[i] = (c < 20) ? *(const i32x4*)(xrow + c * 16)
                                             : ld16_nc(hrow + (c - 20) * 16);
            }
            vmcnt0();
#pragma unroll
            for (int i = 0; i < 7; ++i) {
                int c = sl8 + 8 * i;
                if (c < 52) *(i32x4*)(rowp + ((c * 16) ^ xv)) = vb[i];
            }
        } else {
            // 64 chunks/row: 32 h0 + 32 h1 (both nc)
            const char* h0row = h0b + (size_t)((t + 1) & 15) * 131072 + (size_t)brow_s * 512;
            const char* h1row = h1b + (size_t)t * 131072 + (size_t)brow_s * 512;
            i32x4 vb[8];
#pragma unroll
            for (int i = 0; i < 8; ++i) {
                int c = sl8 + 8 * i;
                vb[i] = (c < 32) ? ld16_nc(h0row + c * 16) : ld16_nc(h1row + (c - 32) * 16);
            }
            vmcnt0();
#pragma unroll
            for (int i = 0; i < 8; ++i) {
                int c = sl8 + 8 * i;
                *(i32x4*)(rowp + ((c * 16) ^ xv)) = vb[i];
            }
        }
        __syncthreads();

        // ---- MFMA: wave (g,kh) -> gate g, K-half kh, 64 rows x 16 cols ----
        f32x4 acc[4];
#pragma unroll
        for (int tm = 0; tm < 4; ++tm) {
            acc[tm] = f32x4{ binit, binit, binit, binit };
            const unsigned char* rp = smem + (tm * 16 + c0) * 1024;
            const int xr = (c0 & 7) << 4;
#pragma unroll
            for (int ksl = 0; ksl < 8; ++ksl) {
                if (ksl < kscnt) {
                    int ks = ksbase + ksl;
                    bf16x8 af = *(const bf16x8*)(rp + ((ks * 64 + kq * 16) ^ xr));
                    acc[tm] = __builtin_amdgcn_mfma_f32_16x16x32_bf16(af, Bf[ksl], acc[tm], 0, 0, 0);
                }
            }
        }
        __syncthreads();   // all A reads done -> overlay gx

        // ---- gate exchange: gx[kh][g][row64][col16], stride 20 f32 ----
        {
            const int gxo = kh * 5120;
#pragma unroll
            for (int tm = 0; tm < 4; ++tm) {
#pragma unroll
                for (int r = 0; r < 4; ++r)
                    gx[gxo + (g * 64 + tm * 16 + kq * 4 + r) * 20 + c0] = acc[tm][r];
            }
        }
        __syncthreads();

        // ---- activations: thread owns (row tid>>3, cols (tid&7)*2 .. +1) ----
        float hv[2];
        {
            const int row = tid >> 3, cb = (tid & 7) * 2;
#pragma unroll
            for (int j = 0; j < 2; ++j) {
                int col = cb + j;
                float iv = gx[(0 * 64 + row) * 20 + col] + gx[5120 + (0 * 64 + row) * 20 + col];
                float fv = gx[(1 * 64 + row) * 20 + col] + gx[5120 + (1 * 64 + row) * 20 + col];
                float gv = gx[(2 * 64 + row) * 20 + col] + gx[5120 + (2 * 64 + row) * 20 + col];
                float ov = gx[(3 * 64 + row) * 20 + col] + gx[5120 + (3 * 64 + row) * 20 + col];
                float cn = sigm(fv) * cst[j] + sigm(iv) * tanh_(gv);
                cst[j] = cn;
                hv[j] = sigm(ov) * tanh_(cn);
            }
        }
        // ---- h store: one 4B sc0sc1 store per thread ----
        {
            int browo = m * 64 + (tid >> 3);
            int colg = n * 16 + (tid & 7) * 2;
            int u = (int)((unsigned)f2bf(hv[0]) | ((unsigned)f2bf(hv[1]) << 16));
            unsigned* o;
            if (LAYER == 0)
                o = (unsigned*)h0s + (size_t)((t + 1) & 15) * 32768 + (size_t)browo * 128 + colg / 2;
            else
                o = (unsigned*)h1s + (size_t)(t + 1) * 32768 + (size_t)browo * 128 + colg / 2;
            st4_nc(o, u);
        }
        vmcnt0();
        __syncthreads();
        if (tid == 0)
            st4_nc(flags + (LAYER ? 2048 : 0) + ((t & 31) * 4 + m) * 16 + n, t + 1);
    }
}

__global__ __launch_bounds__(512, 2) void lstm_kernel(
    const u16* __restrict__ combined, const u16* __restrict__ Bbuf,
    const float* __restrict__ bsum,
    u16* h0s, u16* h1s, int* flags)
{
    __shared__ __align__(16) unsigned char smem[65536];
    int bid = blockIdx.x;
    int L = bid >> 6, r = bid & 63;
    int m = r >> 4, n = r & 15;
    if (L == 0)
        lstm_wg<0>(m, n, combined, Bbuf, bsum, h0s, h1s, flags, smem);
    else
        lstm_wg<1>(m, n, combined, Bbuf, bsum, h0s, h1s, flags, smem);
}

// ---------------- attention pooling + fc1 ----------------
// h1s layout: [t+1][256 rows][256 cols] bf16 (slot stride 65536 u16)
__global__ __launch_bounds__(256) void attn_kernel(
    const u16* __restrict__ h1s, const float* __restrict__ aw, const float* __restrict__ ab,
    const float* __restrict__ fc1w, const float* __restrict__ fc1b,
    float* __restrict__ attw_out, u16* __restrict__ xbf)
{
    int b = blockIdx.x, tid = threadIdx.x, wv = tid >> 6, ln = tid & 63;
    __shared__ float s_aw[256];
    __shared__ float s_sc[104];
    __shared__ float s_red[8];
    __shared__ float s_ctx[256];
    s_aw[tid] = aw[tid];
    __syncthreads();
    for (int t = wv; t < SEQ; t += 4) {
        const u16* hr = h1s + (size_t)(t + 1) * 65536 + (size_t)b * 256;
        ushort4 hv = ((const ushort4*)hr)[ln];
        float pval = bf2f(hv.x) * s_aw[4 * ln] + bf2f(hv.y) * s_aw[4 * ln + 1] +
                     bf2f(hv.z) * s_aw[4 * ln + 2] + bf2f(hv.w) * s_aw[4 * ln + 3];
#pragma unroll
        for (int off = 32; off; off >>= 1) pval += __shfl_xor(pval, off);
        if (ln == 0) s_sc[t] = pval + ab[0];
    }
    __syncthreads();
    float v = (tid < SEQ) ? s_sc[tid] : -1e30f;
    float m = v;
#pragma unroll
    for (int off = 32; off; off >>= 1) m = fmaxf(m, __shfl_xor(m, off));
    if (ln == 0) s_red[wv] = m;
    __syncthreads();
    m = fmaxf(fmaxf(s_red[0], s_red[1]), fmaxf(s_red[2], s_red[3]));
    float e = (tid < SEQ) ? __expf(v - m) : 0.f;
    float ss = e;
#pragma unroll
    for (int off = 32; off; off >>= 1) ss += __shfl_xor(ss, off);
    if (ln == 0) s_red[4 + wv] = ss;
    __syncthreads();
    float denom = s_red[4] + s_red[5] + s_red[6] + s_red[7];
    float awt = e / denom;
    if (tid < SEQ) {
        attw_out[(size_t)b * SEQ + tid] = awt;
        s_sc[tid] = awt;
    }
    __syncthreads();
    float acc = 0.f;
    for (int t = 0; t < SEQ; ++t)
        acc += s_sc[t] * bf2f(h1s[(size_t)(t + 1) * 65536 + (size_t)b * 256 + tid]);
    s_ctx[tid] = acc;
    __syncthreads();
    if (tid < 128) {
        const float* wr = fc1w + tid * 256;
        float d = fc1b[tid];
        for (int k = 0; k < 256; k += 4) {
            float4 w4 = *(const float4*)(wr + k);
            d += w4.x * s_ctx[k] + w4.y * s_ctx[k + 1] + w4.z * s_ctx[k + 2] + w4.w * s_ctx[k + 3];
        }
        float x = fmaxf(d, 0.f);
        xbf[b * 128 + tid] = f2bf(x);
    }
}

// ---------------- fc2: logits = x @ fc2_w^T + b ----------------
__global__ __launch_bounds__(256) void fc2_kernel(
    const u16* __restrict__ xbf, const float* __restrict__ w,
    const float* __restrict__ bias, float* __restrict__ out)
{
    int n0 = blockIdx.x * 16;
    int tid = threadIdx.x, wv = tid >> 6, ln = tid & 63;
    int c0 = ln & 15, kq = ln >> 4;
    int n = n0 + c0;
    int nc = (n > 50000) ? 50000 : n;
    bf16x8 Bf[4];
#pragma unroll
    for (int ks = 0; ks < 4; ++ks) {
        const float* src = w + (size_t)nc * 128 + ks * 32 + kq * 8;
        bf16x8 tb;
#pragma unroll
        for (int i = 0; i < 8; ++i) tb[i] = (short)f2bf(src[i]);
        Bf[ks] = tb;
    }
    float bv = bias[nc];
    int bb = wv * 64;
#pragma unroll
    for (int q = 0; q < 4; ++q) {
        const u16* xr = xbf + (bb + q * 16 + c0) * 128;
        f32x4 acc = { bv, bv, bv, bv };
#pragma unroll
        for (int ks = 0; ks < 4; ++ks) {
            bf16x8 a = *(const bf16x8*)(xr + ks * 32 + kq * 8);
            acc = __builtin_amdgcn_mfma_f32_16x16x32_bf16(a, Bf[ks], acc, 0, 0, 0);
        }
        if (n <= 50000) {
#pragma unroll
            for (int r = 0; r < 4; ++r)
                out[(size_t)(bb + q * 16 + kq * 4 + r) * 50001 + n] = acc[r];
        }
    }
}

extern "C" void kernel_launch(void* const* d_in, const int* in_sizes, int n_in,
                              void* d_out, int out_size, void* d_ws, size_t ws_size,
                              hipStream_t stream) {
    (void)in_sizes; (void)n_in; (void)out_size; (void)ws_size;
    const int*   seqs = (const int*)d_in[0];
    const int*   p2c  = (const int*)d_in[1];
    const float* ptab = (const float*)d_in[2];
    const float* ctab = (const float*)d_in[3];
    const float* Wih0 = (const float*)d_in[4];
    const float* Whh0 = (const float*)d_in[5];
    const float* bih0 = (const float*)d_in[6];
    const float* bhh0 = (const float*)d_in[7];
    const float* Wih1 = (const float*)d_in[8];
    const float* Whh1 = (const float*)d_in[9];
    const float* bih1 = (const float*)d_in[10];
    const float* bhh1 = (const float*)d_in[11];
    const float* aw   = (const float*)d_in[12];
    const float* ab   = (const float*)d_in[13];
    const float* fc1w = (const float*)d_in[14];
    const float* fc1b = (const float*)d_in[15];
    const float* fc2w = (const float*)d_in[16];
    const float* fc2b = (const float*)d_in[17];

    char* wsb = (char*)d_ws;
    int*   flags    = (int*)wsb;                     // 64KB (per-step slot lines)
    u16*   h0s      = (u16*)(wsb + 65536);           // 16 slots x 131072 = 2097152
    u16*   h1s      = (u16*)(wsb + 2162688);         // 101 slots x 131072 = 13238272
    u16*   Bbuf     = (u16*)(wsb + 15400960);        // 1900544
    float* bsum     = (float*)(wsb + 17301504);      // 8192
    u16*   combined = (u16*)(wsb + 17309696);        // 8192000
    u16*   xbf      = (u16*)(wsb + 25501696);        // 65536
    float* logits   = (float*)d_out;
    float* attw_out = logits + (size_t)BATCH * NPROD;

    // zero: flags + entire h0s ring + h1s slot 0 (initial hidden states)
    (void)hipMemsetAsync(d_ws, 0, 2293760, stream);
    prep_kernel<<<472, 256, 0, stream>>>(Wih0, Whh0, Wih1, Whh1, bih0, bhh0, bih1, bhh1, Bbuf, bsum);
    embed_kernel<<<6400, 256, 0, stream>>>(seqs, p2c, ptab, ctab, combined);
    lstm_kernel<<<128, 512, 0, stream>>>(combined, Bbuf, bsum, h0s, h1s, flags);
    attn_kernel<<<256, 256, 0, stream>>>(h1s, aw, ab, fc1w, fc1b, attw_out, xbf);
    fc2_kernel<<<3126, 256, 0, stream>>>(xbf, fc2w, fc2b, logits);
}

// Round 13
// 515.966 us; speedup vs baseline: 1.9597x; 1.2838x over previous
//
#include <hip/hip_runtime.h>
#include <hip/hip_bf16.h>

typedef unsigned short u16;
typedef __attribute__((ext_vector_type(8))) short bf16x8;
typedef __attribute__((ext_vector_type(4))) float f32x4;
typedef __attribute__((ext_vector_type(4))) int i32x4;
typedef __attribute__((ext_vector_type(2))) int i32x2;

#define NPROD 50001
#define SEQ 100
#define BATCH 256
#define HID 256

// Bbuf chunks: layer0 16n*4g*13ks*64ln = 53248, layer1 16*4*16*64 = 65536
#define L0_CHUNKS 53248
#define L1_CHUNKS 65536
#define L1_BASE_U16 (L0_CHUNKS * 8)

__device__ inline float bf2f(u16 u) {
    union { unsigned u; float f; } v; v.u = ((unsigned)u) << 16; return v.f;
}
__device__ inline u16 f2bf(float x) {
    unsigned u = __float_as_uint(x);
    unsigned r = (u + 0x7FFFu + ((u >> 16) & 1u)) >> 16;
    return (u16)r;
}
__device__ inline float sigm(float x) { return 1.f / (1.f + __expf(-x)); }
__device__ inline float tanh_(float x) { return 1.f - 2.f / (1.f + __expf(2.f * x)); }

// Cross-XCD-coherent (bypass L1+L2): sc0 sc1. Batched: many in flight, one s_waitcnt.
__device__ inline i32x4 ld16_nc(const void* p) {
    i32x4 r;
    asm volatile("global_load_dwordx4 %0, %1, off sc0 sc1" : "=&v"(r) : "v"(p) : "memory");
    return r;
}
__device__ inline void st4_nc(void* p, int v) {
    asm volatile("global_store_dword %0, %1, off sc0 sc1" :: "v"(p), "v"(v) : "memory");
}
__device__ inline void vmcnt0() {
    asm volatile("s_waitcnt vmcnt(0)" ::: "memory");
    __builtin_amdgcn_sched_barrier(0);
}
// parallel flag spin: 4 slots per lane, pass when all >= tgt (signed)
__device__ inline void spin4(const int* p, int tgt) {
    for (;;) {
        i32x4 v = ld16_nc(p);
        if (v[0] >= tgt && v[1] >= tgt && v[2] >= tgt && v[3] >= tgt) return;
        __builtin_amdgcn_s_sleep(1);
    }
}

// flag line address (ints): group (L,m), step t, quarter q holds slots n=4q..4q+3
// at dwords 0..3 of a dedicated 64B line (producers spread across 4 lines).
__device__ inline int flagline(int L, int t, int m, int q) {
    return (L ? 8192 : 0) + ((((t & 31) * 4 + m) * 4 + q) * 16);
}

// ---------------- weight prep: f32 -> bf16 MFMA B-fragments + bias sums ----------------
// Bbuf (per layer): i = ((n*4 + g)*KS + ks)*64 + ln, 8 u16 each.
// grow = g*256 + n*16 + (ln&15); k = ks*32 + (ln>>4)*8 + e; k-concat [x | h].
__global__ __launch_bounds__(256) void prep_kernel(
    const float* __restrict__ Wih0, const float* __restrict__ Whh0,
    const float* __restrict__ Wih1, const float* __restrict__ Whh1,
    const float* __restrict__ bih0, const float* __restrict__ bhh0,
    const float* __restrict__ bih1, const float* __restrict__ bhh1,
    u16* __restrict__ Bbuf, float* __restrict__ bsum)
{
    int idx = blockIdx.x * 256 + threadIdx.x;
    if (idx < L0_CHUNKS + L1_CHUNKS) {
        int L, KS, i;
        if (idx < L0_CHUNKS) { L = 0; KS = 13; i = idx; }
        else { L = 1; KS = 16; i = idx - L0_CHUNKS; }
        int ln = i & 63; int q = i >> 6;
        int ks = q % KS; int q2 = q / KS;
        int g = q2 & 3; int n = q2 >> 2;
        int grow = g * 256 + n * 16 + (ln & 15);
        int k0 = ks * 32 + (ln >> 4) * 8;
        bf16x8 v;
#pragma unroll
        for (int e = 0; e < 8; ++e) {
            int k = k0 + e;
            float f;
            if (L == 0) f = (k < 160) ? Wih0[(size_t)grow * 160 + k] : Whh0[(size_t)grow * 256 + (k - 160)];
            else        f = (k < 256) ? Wih1[(size_t)grow * 256 + k] : Whh1[(size_t)grow * 256 + (k - 256)];
            v[e] = (short)f2bf(f);
        }
        size_t off = (size_t)(L ? L1_BASE_U16 : 0) + ((size_t)i) * 8;
        *(bf16x8*)(Bbuf + off) = v;
    } else if (idx < L0_CHUNKS + L1_CHUNKS + 2048) {
        int j = idx - (L0_CHUNKS + L1_CHUNKS);
        int L = j >> 10, r = j & 1023;
        bsum[j] = L ? (bih1[r] + bhh1[r]) : (bih0[r] + bhh0[r]);
    }
}

// ---------------- embedding + mean-pool + category ----------------
// combined layout: [t][b][160] (t-major -> step slice is one contiguous 2MB block)
__global__ __launch_bounds__(256) void embed_kernel(
    const int* __restrict__ seqs, const int* __restrict__ p2c,
    const float* __restrict__ ptab, const float* __restrict__ ctab,
    u16* __restrict__ combined)
{
    int gw = (blockIdx.x * 256 + threadIdx.x) >> 6;   // gw = b*SEQ + s
    int ln = threadIdx.x & 63;
    int b = gw / SEQ, s = gw - b * SEQ;
    const int* basket = seqs + (size_t)gw * 20;
    int idx = (ln < 20) ? basket[ln] : 0;
    unsigned long long nz = __ballot(idx != 0);
    int fp = 0;
    if (nz != 0ull) {
        int fl = __ffsll(nz) - 1;
        fp = __shfl(idx, fl);
    }
    float a0 = 0.f, a1 = 0.f;
#pragma unroll
    for (int k = 0; k < 20; ++k) {
        int pk = __shfl(idx, k);
        float2 v = *(const float2*)(ptab + (size_t)pk * 128 + 2 * ln);
        a0 += v.x; a1 += v.y;
    }
    const float inv = 1.0f / 20.0f;
    u16* crow = combined + ((size_t)s * BATCH + b) * 160;
    ushort2 st; st.x = f2bf(a0 * inv); st.y = f2bf(a1 * inv);
    ((ushort2*)crow)[ln] = st;
    int cat = p2c[fp];
    if (ln < 16) {
        float2 cv = *(const float2*)(ctab + (size_t)cat * 32 + 2 * ln);
        ushort2 s2; s2.x = f2bf(cv.x); s2.y = f2bf(cv.y);
        ((ushort2*)(crow + 128))[ln] = s2;
    }
}

// ---------------- persistent 2-layer LSTM, K-split 8-wave WGs ----------------
// 128 WGs x 512 thr = 2 layers x 4 batch-slices(m: 64 rows) x 16 col-slices(n).
// Wave w = (gate g=w&3, K-half kh=w>>2): Bf register-resident (r12).
// r13 changes: combined t-major (HBM fetch once), x loads issued BEFORE the
// flag spin (latency hidden under poll), flag slots spread over 4 lines/group.
template <int LAYER>
__device__ void lstm_wg(int m, int n,
    const u16* __restrict__ combined, const u16* __restrict__ Bbuf,
    const float* __restrict__ bsum,
    u16* h0s, u16* h1s, int* flags, unsigned char* smem)
{
    constexpr int KS = (LAYER == 0) ? 13 : 16;
    constexpr int H0 = (LAYER == 0) ? 7 : 8;    // kh=0 ks-count
    const int tid = threadIdx.x;
    const int wv = tid >> 6, ln = tid & 63;
    const int c0 = ln & 15, kq = ln >> 4;
    const int g = wv & 3, kh = wv >> 2;
    const int ksbase = kh ? H0 : 0;
    const int kscnt  = kh ? (KS - H0) : H0;

    // ---- preload B fragments: wave (g,kh) holds its K-half of gate g ----
    bf16x8 Bf[8];
#pragma unroll
    for (int ksl = 0; ksl < 8; ++ksl) {
        if (ksl < kscnt) {
            size_t off = (size_t)(LAYER ? L1_BASE_U16 : 0) +
                         ((size_t)(((n * 4 + g) * KS + ksbase + ksl) * 64 + ln)) * 8;
            Bf[ksl] = *(const bf16x8*)(Bbuf + off);
        }
    }
    const float binit = kh ? 0.f : bsum[LAYER * 1024 + g * 256 + n * 16 + c0];

    float cst[2] = {0.f, 0.f};
    const int srow = tid >> 3, sl8 = tid & 7;     // staging: 8 threads per row
    const int brow_s = m * 64 + srow;
    const char* h0b = (const char*)h0s;
    const char* h1b = (const char*)h1s;
    unsigned char* rowp = smem + srow * 1024;
    const int xv = (srow & 7) << 4;
    float* gx = (float*)smem;                      // overlay: gx[2][4][64][20]

    for (int t = 0; t < SEQ; ++t) {
        // ---- L0: issue x loads (plain cached, flag-independent) BEFORE spin ----
        i32x4 xb0, xb1, xb2;
        if (LAYER == 0) {
            const char* xrow = (const char*)(combined + ((size_t)t * BATCH + brow_s) * 160);
            xb0 = *(const i32x4*)(xrow + sl8 * 16);
            xb1 = *(const i32x4*)(xrow + (sl8 + 8) * 16);
            if (sl8 < 4) xb2 = *(const i32x4*)(xrow + (sl8 + 16) * 16);
        }
        // ---- lane-parallel polls, 4 lines per group (producers spread) ----
        if (LAYER == 0) {
            if (t > 0 && tid < 4)
                spin4(flags + flagline(0, t - 1, m, tid), t);
            if (t >= 16 && tid >= 4 && tid < 8)   // ring: L1 done step t-16
                spin4(flags + flagline(1, t - 16, m, tid - 4), t - 15);
        } else {
            if (tid < 4)                           // L0 done step t
                spin4(flags + flagline(0, t, m, tid), t + 1);
            if (t > 0 && tid >= 4 && tid < 8)      // own group done step t-1
                spin4(flags + flagline(1, t - 1, m, tid - 4), t);
        }
        __syncthreads();

        // ---- stage A (64 rows x K bf16) into LDS; 8 threads per row ----
        if (LAYER == 0) {
            const char* hrow = h0b + (size_t)(t & 15) * 131072 + (size_t)brow_s * 512;
            i32x4 hb[4];
#pragma unroll
            for (int i = 0; i < 4; ++i) hb[i] = ld16_nc(hrow + (sl8 + 8 * i) * 16);
            vmcnt0();
            *(i32x4*)(rowp + ((sl8 * 16) ^ xv)) = xb0;
            *(i32x4*)(rowp + (((sl8 + 8) * 16) ^ xv)) = xb1;
            if (sl8 < 4) *(i32x4*)(rowp + (((sl8 + 16) * 16) ^ xv)) = xb2;
#pragma unroll
            for (int i = 0; i < 4; ++i)
                *(i32x4*)(rowp + (((20 + sl8 + 8 * i) * 16) ^ xv)) = hb[i];
        } else {
            // 64 chunks/row: 32 h0 + 32 h1 (both nc)
            const char* h0row = h0b + (size_t)((t + 1) & 15) * 131072 + (size_t)brow_s * 512;
            const char* h1row = h1b + (size_t)t * 131072 + (size_t)brow_s * 512;
            i32x4 vb[8];
#pragma unroll
            for (int i = 0; i < 8; ++i) {
                int c = sl8 + 8 * i;
                vb[i] = (c < 32) ? ld16_nc(h0row + c * 16) : ld16_nc(h1row + (c - 32) * 16);
            }
            vmcnt0();
#pragma unroll
            for (int i = 0; i < 8; ++i) {
                int c = sl8 + 8 * i;
                *(i32x4*)(rowp + ((c * 16) ^ xv)) = vb[i];
            }
        }
        __syncthreads();

        // ---- MFMA: wave (g,kh) -> gate g, K-half kh, 64 rows x 16 cols ----
        f32x4 acc[4];
#pragma unroll
        for (int tm = 0; tm < 4; ++tm) {
            acc[tm] = f32x4{ binit, binit, binit, binit };
            const unsigned char* rp = smem + (tm * 16 + c0) * 1024;
            const int xr = (c0 & 7) << 4;
#pragma unroll
            for (int ksl = 0; ksl < 8; ++ksl) {
                if (ksl < kscnt) {
                    int ks = ksbase + ksl;
                    bf16x8 af = *(const bf16x8*)(rp + ((ks * 64 + kq * 16) ^ xr));
                    acc[tm] = __builtin_amdgcn_mfma_f32_16x16x32_bf16(af, Bf[ksl], acc[tm], 0, 0, 0);
                }
            }
        }
        __syncthreads();   // all A reads done -> overlay gx

        // ---- gate exchange: gx[kh][g][row64][col16], stride 20 f32 ----
        {
            const int gxo = kh * 5120;
#pragma unroll
            for (int tm = 0; tm < 4; ++tm) {
#pragma unroll
                for (int r = 0; r < 4; ++r)
                    gx[gxo + (g * 64 + tm * 16 + kq * 4 + r) * 20 + c0] = acc[tm][r];
            }
        }
        __syncthreads();

        // ---- activations: thread owns (row tid>>3, cols (tid&7)*2 .. +1) ----
        float hv[2];
        {
            const int row = tid >> 3, cb = (tid & 7) * 2;
#pragma unroll
            for (int j = 0; j < 2; ++j) {
                int col = cb + j;
                float iv = gx[(0 * 64 + row) * 20 + col] + gx[5120 + (0 * 64 + row) * 20 + col];
                float fv = gx[(1 * 64 + row) * 20 + col] + gx[5120 + (1 * 64 + row) * 20 + col];
                float gv = gx[(2 * 64 + row) * 20 + col] + gx[5120 + (2 * 64 + row) * 20 + col];
                float ov = gx[(3 * 64 + row) * 20 + col] + gx[5120 + (3 * 64 + row) * 20 + col];
                float cn = sigm(fv) * cst[j] + sigm(iv) * tanh_(gv);
                cst[j] = cn;
                hv[j] = sigm(ov) * tanh_(cn);
            }
        }
        // ---- h store: one 4B sc0sc1 store per thread ----
        {
            int browo = m * 64 + (tid >> 3);
            int colg = n * 16 + (tid & 7) * 2;
            int u = (int)((unsigned)f2bf(hv[0]) | ((unsigned)f2bf(hv[1]) << 16));
            unsigned* o;
            if (LAYER == 0)
                o = (unsigned*)h0s + (size_t)((t + 1) & 15) * 32768 + (size_t)browo * 128 + colg / 2;
            else
                o = (unsigned*)h1s + (size_t)(t + 1) * 32768 + (size_t)browo * 128 + colg / 2;
            st4_nc(o, u);
        }
        vmcnt0();
        __syncthreads();
        if (tid == 0)
            st4_nc(flags + flagline(LAYER, t, m, n >> 2) + (n & 3), t + 1);
    }
}

__global__ __launch_bounds__(512, 2) void lstm_kernel(
    const u16* __restrict__ combined, const u16* __restrict__ Bbuf,
    const float* __restrict__ bsum,
    u16* h0s, u16* h1s, int* flags)
{
    __shared__ __align__(16) unsigned char smem[65536];
    int bid = blockIdx.x;
    int L = bid >> 6, r = bid & 63;
    int m = r >> 4, n = r & 15;
    if (L == 0)
        lstm_wg<0>(m, n, combined, Bbuf, bsum, h0s, h1s, flags, smem);
    else
        lstm_wg<1>(m, n, combined, Bbuf, bsum, h0s, h1s, flags, smem);
}

// ---------------- attention pooling + fc1 ----------------
// h1s layout: [t+1][256 rows][256 cols] bf16 (slot stride 65536 u16)
__global__ __launch_bounds__(256) void attn_kernel(
    const u16* __restrict__ h1s, const float* __restrict__ aw, const float* __restrict__ ab,
    const float* __restrict__ fc1w, const float* __restrict__ fc1b,
    float* __restrict__ attw_out, u16* __restrict__ xbf)
{
    int b = blockIdx.x, tid = threadIdx.x, wv = tid >> 6, ln = tid & 63;
    __shared__ float s_aw[256];
    __shared__ float s_sc[104];
    __shared__ float s_red[8];
    __shared__ float s_ctx[256];
    s_aw[tid] = aw[tid];
    __syncthreads();
    for (int t = wv; t < SEQ; t += 4) {
        const u16* hr = h1s + (size_t)(t + 1) * 65536 + (size_t)b * 256;
        ushort4 hv = ((const ushort4*)hr)[ln];
        float pval = bf2f(hv.x) * s_aw[4 * ln] + bf2f(hv.y) * s_aw[4 * ln + 1] +
                     bf2f(hv.z) * s_aw[4 * ln + 2] + bf2f(hv.w) * s_aw[4 * ln + 3];
#pragma unroll
        for (int off = 32; off; off >>= 1) pval += __shfl_xor(pval, off);
        if (ln == 0) s_sc[t] = pval + ab[0];
    }
    __syncthreads();
    float v = (tid < SEQ) ? s_sc[tid] : -1e30f;
    float m = v;
#pragma unroll
    for (int off = 32; off; off >>= 1) m = fmaxf(m, __shfl_xor(m, off));
    if (ln == 0) s_red[wv] = m;
    __syncthreads();
    m = fmaxf(fmaxf(s_red[0], s_red[1]), fmaxf(s_red[2], s_red[3]));
    float e = (tid < SEQ) ? __expf(v - m) : 0.f;
    float ss = e;
#pragma unroll
    for (int off = 32; off; off >>= 1) ss += __shfl_xor(ss, off);
    if (ln == 0) s_red[4 + wv] = ss;
    __syncthreads();
    float denom = s_red[4] + s_red[5] + s_red[6] + s_red[7];
    float awt = e / denom;
    if (tid < SEQ) {
        attw_out[(size_t)b * SEQ + tid] = awt;
        s_sc[tid] = awt;
    }
    __syncthreads();
    float acc = 0.f;
    for (int t = 0; t < SEQ; ++t)
        acc += s_sc[t] * bf2f(h1s[(size_t)(t + 1) * 65536 + (size_t)b * 256 + tid]);
    s_ctx[tid] = acc;
    __syncthreads();
    if (tid < 128) {
        const float* wr = fc1w + tid * 256;
        float d = fc1b[tid];
        for (int k = 0; k < 256; k += 4) {
            float4 w4 = *(const float4*)(wr + k);
            d += w4.x * s_ctx[k] + w4.y * s_ctx[k + 1] + w4.z * s_ctx[k + 2] + w4.w * s_ctx[k + 3];
        }
        float x = fmaxf(d, 0.f);
        xbf[b * 128 + tid] = f2bf(x);
    }
}

// ---------------- fc2: logits = x @ fc2_w^T + b ----------------
__global__ __launch_bounds__(256) void fc2_kernel(
    const u16* __restrict__ xbf, const float* __restrict__ w,
    const float* __restrict__ bias, float* __restrict__ out)
{
    int n0 = blockIdx.x * 16;
    int tid = threadIdx.x, wv = tid >> 6, ln = tid & 63;
    int c0 = ln & 15, kq = ln >> 4;
    int n = n0 + c0;
    int nc = (n > 50000) ? 50000 : n;
    bf16x8 Bf[4];
#pragma unroll
    for (int ks = 0; ks < 4; ++ks) {
        const float* src = w + (size_t)nc * 128 + ks * 32 + kq * 8;
        bf16x8 tb;
#pragma unroll
        for (int i = 0; i < 8; ++i) tb[i] = (short)f2bf(src[i]);
        Bf[ks] = tb;
    }
    float bv = bias[nc];
    int bb = wv * 64;
#pragma unroll
    for (int q = 0; q < 4; ++q) {
        const u16* xr = xbf + (bb + q * 16 + c0) * 128;
        f32x4 acc = { bv, bv, bv, bv };
#pragma unroll
        for (int ks = 0; ks < 4; ++ks) {
            bf16x8 a = *(const bf16x8*)(xr + ks * 32 + kq * 8);
            acc = __builtin_amdgcn_mfma_f32_16x16x32_bf16(a, Bf[ks], acc, 0, 0, 0);
        }
        if (n <= 50000) {
#pragma unroll
            for (int r = 0; r < 4; ++r)
                out[(size_t)(bb + q * 16 + kq * 4 + r) * 50001 + n] = acc[r];
        }
    }
}

extern "C" void kernel_launch(void* const* d_in, const int* in_sizes, int n_in,
                              void* d_out, int out_size, void* d_ws, size_t ws_size,
                              hipStream_t stream) {
    (void)in_sizes; (void)n_in; (void)out_size; (void)ws_size;
    const int*   seqs = (const int*)d_in[0];
    const int*   p2c  = (const int*)d_in[1];
    const float* ptab = (const float*)d_in[2];
    const float* ctab = (const float*)d_in[3];
    const float* Wih0 = (const float*)d_in[4];
    const float* Whh0 = (const float*)d_in[5];
    const float* bih0 = (const float*)d_in[6];
    const float* bhh0 = (const float*)d_in[7];
    const float* Wih1 = (const float*)d_in[8];
    const float* Whh1 = (const float*)d_in[9];
    const float* bih1 = (const float*)d_in[10];
    const float* bhh1 = (const float*)d_in[11];
    const float* aw   = (const float*)d_in[12];
    const float* ab   = (const float*)d_in[13];
    const float* fc1w = (const float*)d_in[14];
    const float* fc1b = (const float*)d_in[15];
    const float* fc2w = (const float*)d_in[16];
    const float* fc2b = (const float*)d_in[17];

    char* wsb = (char*)d_ws;
    int*   flags    = (int*)wsb;                     // 64KB (per-step, 4 lines/group)
    u16*   h0s      = (u16*)(wsb + 65536);           // 16 slots x 131072 = 2097152
    u16*   h1s      = (u16*)(wsb + 2162688);         // 101 slots x 131072 = 13238272
    u16*   Bbuf     = (u16*)(wsb + 15400960);        // 1900544
    float* bsum     = (float*)(wsb + 17301504);      // 8192
    u16*   combined = (u16*)(wsb + 17309696);        // [100][256][160] = 8192000
    u16*   xbf      = (u16*)(wsb + 25501696);        // 65536
    float* logits   = (float*)d_out;
    float* attw_out = logits + (size_t)BATCH * NPROD;

    // zero: flags + entire h0s ring + h1s slot 0 (initial hidden states)
    (void)hipMemsetAsync(d_ws, 0, 2293760, stream);
    prep_kernel<<<472, 256, 0, stream>>>(Wih0, Whh0, Wih1, Whh1, bih0, bhh0, bih1, bhh1, Bbuf, bsum);
    embed_kernel<<<6400, 256, 0, stream>>>(seqs, p2c, ptab, ctab, combined);
    lstm_kernel<<<128, 512, 0, stream>>>(combined, Bbuf, bsum, h0s, h1s, flags);
    attn_kernel<<<256, 256, 0, stream>>>(h1s, aw, ab, fc1w, fc1b, attw_out, xbf);
    fc2_kernel<<<3126, 256, 0, stream>>>(xbf, fc2w, fc2b, logits);
}